// Round 10
// baseline (576.166 us; speedup 1.0000x reference)
//
#include <hip/hip_runtime.h>
#include <hip/hip_bf16.h>
#include <hip/hip_fp16.h>
#include <cstdint>

#define N_NODES 100000
#define N_EDGES 1600000
#define N_GRAPHS 64
#define F_IN 64
#define F_MID 128
#define F_OUT 64

typedef unsigned int uint32;

// ---- dtype-agnostic accessors (flags[0]=1 → floats are fp32; flags[1]=1 → ints are int64)
__device__ __forceinline__ float ldF(const void* p, size_t i, int f32) {
    return f32 ? ((const float*)p)[i]
               : __bfloat162float(((const __hip_bfloat16*)p)[i]);
}
__device__ __forceinline__ int ldI(const void* p, size_t i, int i64) {
    return i64 ? (int)((const long long*)p)[i] : ((const int*)p)[i];
}
__device__ __forceinline__ void stF(void* p, size_t i, float v, int f32) {
    if (f32) ((float*)p)[i] = v;
    else     ((__hip_bfloat16*)p)[i] = __float2bfloat16(v);
}

// ---- fp16x2 pack/unpack (SCALAR unions only — arrays of unions spill to scratch!) ----
union H2U { uint32 u; __half2 h; };
__device__ __forceinline__ float2 up16(uint32 u) {
    H2U c; c.u = u;
    return __half22float2(c.h);
}
__device__ __forceinline__ __half2 u2h(uint32 u) {
    H2U c; c.u = u;
    return c.h;
}
__device__ __forceinline__ uint32 pk16(float a, float b) {
    H2U c; c.h = __floats2half2_rn(a, b);
    return c.u;
}
__device__ __forceinline__ unsigned short bfbits(float f) {
    __hip_bfloat16 b = __float2bfloat16(f);
    return *(unsigned short*)&b;
}

// ---------------- dtype sniffer ----------------------------------------------------
__global__ void GCNEncoder_77214922048129_kernel(const void* x, const void* ei,
                                                 int* flags) {
    __shared__ int cnt_weird, cnt_zero;
    if (threadIdx.x == 0) { cnt_weird = 0; cnt_zero = 0; }
    __syncthreads();
    const unsigned short* u = (const unsigned short*)x;
    int w = 0;
    for (int i = threadIdx.x; i < 2048; i += 256) {
        int e = (u[i] >> 7) & 0xFF;
        if (e == 0xFF || e >= 159 || (e > 0 && e <= 95)) w++;
    }
    atomicAdd(&cnt_weird, w);
    const int* ii = (const int*)ei;
    int z = 0;
    for (int i = threadIdx.x; i < 128; i += 256) {
        if (ii[2 * i + 1] == 0) z++;
    }
    atomicAdd(&cnt_zero, z);
    __syncthreads();
    if (threadIdx.x == 0) {
        flags[0] = (cnt_weird > 64) ? 1 : 0;  // fp32 floats
        flags[1] = (cnt_zero > 64) ? 1 : 0;   // int64 indices
    }
}

// ---------------- degree over col (self-loop added analytically) -------------------
__global__ void k_deg(const void* __restrict__ ei, int* __restrict__ deg,
                      const int* __restrict__ flags) {
    const int i64 = flags[1];
    int e = blockIdx.x * blockDim.x + threadIdx.x;
    if (e < N_EDGES) atomicAdd(&deg[ldI(ei, (size_t)N_EDGES + e, i64)], 1);
}

__global__ void k_dinv(const int* __restrict__ deg, float* __restrict__ dinv) {
    int i = blockIdx.x * blockDim.x + threadIdx.x;
    if (i < N_NODES) dinv[i] = rsqrtf((float)deg[i] + 1.0f);  // +1 = self-loop
}

// ---------------- CSR build: 3-stage parallel exclusive scan of deg ----------------
#define NB_SCAN ((N_NODES + 255) / 256)  // 391

__global__ __launch_bounds__(256) void k_bsum(const int* __restrict__ deg,
                                              int* __restrict__ bsum) {
    __shared__ int sh[256];
    int idx = blockIdx.x * 256 + threadIdx.x;
    sh[threadIdx.x] = (idx < N_NODES) ? deg[idx] : 0;
    __syncthreads();
#pragma unroll
    for (int off = 128; off > 0; off >>= 1) {
        if (threadIdx.x < off) sh[threadIdx.x] += sh[threadIdx.x + off];
        __syncthreads();
    }
    if (threadIdx.x == 0) bsum[blockIdx.x] = sh[0];
}

__global__ __launch_bounds__(512) void k_bscan(const int* __restrict__ bsum,
                                               int* __restrict__ bbase) {
    __shared__ int sh[512];
    const int t = threadIdx.x;
    sh[t] = (t < NB_SCAN) ? bsum[t] : 0;
    __syncthreads();
    for (int off = 1; off < 512; off <<= 1) {
        int v = (t >= off) ? sh[t - off] : 0;
        __syncthreads();
        sh[t] += v;
        __syncthreads();
    }
    if (t < NB_SCAN) bbase[t] = (t == 0) ? 0 : sh[t - 1];
}

__global__ __launch_bounds__(256) void k_rowptr(const int* __restrict__ deg,
                                                const int* __restrict__ bbase,
                                                int* __restrict__ rowptr,
                                                int* __restrict__ cursor) {
    __shared__ int sh[256];
    const int t = threadIdx.x;
    const int idx = blockIdx.x * 256 + t;
    const int d = (idx < N_NODES) ? deg[idx] : 0;
    sh[t] = d;
    __syncthreads();
    for (int off = 1; off < 256; off <<= 1) {
        int v = (t >= off) ? sh[t - off] : 0;
        __syncthreads();
        sh[t] += v;
        __syncthreads();
    }
    if (idx < N_NODES) {
        int r = bbase[blockIdx.x] + sh[t] - d;  // exclusive
        rowptr[idx] = r;
        cursor[idx] = r;
    }
    if (idx == 0) rowptr[N_NODES] = N_EDGES;
}

// ---------------- CSR scatter: src[pos(c)] = r -------------------------------------
__global__ __launch_bounds__(256) void k_csr(const void* __restrict__ ei,
                                             int* __restrict__ cursor,
                                             int* __restrict__ src,
                                             const int* __restrict__ flags) {
    const int i64 = flags[1];
    int e = blockIdx.x * blockDim.x + threadIdx.x;
    if (e < N_EDGES) {
        int r = ldI(ei, e, i64);
        int c = ldI(ei, (size_t)N_EDGES + e, i64);
        int pos = atomicAdd(&cursor[c], 1);
        src[pos] = r;
    }
}

// ---------------- xs16[n] = fp16( x[n] * dinv[n] ), packed pairs -------------------
__global__ __launch_bounds__(256) void k_scale(const void* __restrict__ x,
                                               const float* __restrict__ dinv,
                                               uint32* __restrict__ xs16,
                                               const int* __restrict__ flags) {
    const int F32 = flags[0];
    int idx = blockIdx.x * blockDim.x + threadIdx.x;  // feature-pair index
    if (idx < N_NODES * 32) {
        int n = idx >> 5;
        float dv = dinv[n];
        float a = ldF(x, (size_t)idx * 2, F32) * dv;
        float b = ldF(x, (size_t)idx * 2 + 1, F32) * dv;
        xs16[idx] = pk16(a, b);
    }
}

// ------ fused layer1: b128 gather (8 lanes/edge) + GEMM1 + LN + ReLU + GEMM2 -------
// TWO nodes per wave (weight reads amortized); gather: one dwordx4 per 8-lane group
// covers a full 64-feat fp16 row; idx loads prefetched one chunk ahead.
#define G1W 8
__global__ __launch_bounds__(64 * G1W) void k_gather1(
    const int* __restrict__ rowptr, const int* __restrict__ src,
    const uint32* __restrict__ xsu, const float* __restrict__ dinv,
    const void* __restrict__ b1, const void* __restrict__ lnw,
    const void* __restrict__ lnb, const void* __restrict__ W1,
    const void* __restrict__ W2, uint32* __restrict__ a2u,
    const int* __restrict__ flags) {
    const int F32 = flags[0];
    __shared__ uint2  w1d[32 * 64];   // [k2][f]: .x=(W1[2k2][f],W1[2k2+1][f]) .y=same @f+64 ; 16 KB
    __shared__ uint2  w2q[32 * 64];   // [k4][f]: 4 k-values of W2 per entry ; 16 KB
    __shared__ float b1s[F_MID], lnws[F_MID], lnbs[F_MID];
    __shared__ uint32 aggp[G1W][2][32];  // packed agg k-pairs, 2 nodes per wave
    __shared__ uint32 usp[G1W][2][64];   // packed u k-pairs
    for (int i = threadIdx.x; i < 32 * 64; i += 64 * G1W) {
        const int k2 = i >> 6, f = i & 63;
        uint2 w;
        w.x = pk16(ldF(W1, (size_t)(2 * k2) * F_MID + f, F32),
                   ldF(W1, (size_t)(2 * k2 + 1) * F_MID + f, F32));
        w.y = pk16(ldF(W1, (size_t)(2 * k2) * F_MID + f + 64, F32),
                   ldF(W1, (size_t)(2 * k2 + 1) * F_MID + f + 64, F32));
        w1d[i] = w;
    }
    for (int i = threadIdx.x; i < 32 * 64; i += 64 * G1W) {
        const int k4 = i >> 6, f = i & 63;
        uint2 w;
        w.x = pk16(ldF(W2, (size_t)(4 * k4) * F_OUT + f, F32),
                   ldF(W2, (size_t)(4 * k4 + 1) * F_OUT + f, F32));
        w.y = pk16(ldF(W2, (size_t)(4 * k4 + 2) * F_OUT + f, F32),
                   ldF(W2, (size_t)(4 * k4 + 3) * F_OUT + f, F32));
        w2q[i] = w;
    }
    if (threadIdx.x < F_MID) {
        b1s[threadIdx.x] = ldF(b1, threadIdx.x, F32);
        lnws[threadIdx.x] = ldF(lnw, threadIdx.x, F32);
        lnbs[threadIdx.x] = ldF(lnb, threadIdx.x, F32);
    }
    __syncthreads();
    const int wid = threadIdx.x >> 6;
    const int lane = threadIdx.x & 63;
    const int g8 = lane >> 3;   // edge slot within chunk (0..7)
    const int q8 = lane & 7;    // feature-quad (uint4) within row
    const uint4* __restrict__ xsu4 = (const uint4*)xsu;  // row = 8 uint4
    const __half2 hz = __float2half2_rn(0.f);
    const int stride = gridDim.x * G1W * 2;
    for (int base0 = (blockIdx.x * G1W + wid) * 2; base0 < N_NODES; base0 += stride) {
        const int base = __builtin_amdgcn_readfirstlane(base0);  // N_NODES even
        // ================= gather node A then node B (b128, 8 lanes/edge) =========
#pragma unroll
        for (int i = 0; i < 2; ++i) {
            const int n = base + i;
            const int beg = rowptr[n], end = rowptr[n + 1];
            float2 c0 = {0.f, 0.f}, c1 = {0.f, 0.f}, c2 = {0.f, 0.f}, c3 = {0.f, 0.f};
            int pe = beg + g8;
            int pidx = (pe < end) ? src[pe] : -1;
            for (int jj = beg; jj < end; jj += 8) {
                const int idx = pidx;
                const int ne = jj + 8 + g8;
                pidx = (ne < end) ? src[ne] : -1;  // prefetch next chunk's index
                if (idx >= 0) {
                    const uint4 v = xsu4[(size_t)idx * 8 + q8];
                    float2 t;
                    t = up16(v.x); c0.x += t.x; c0.y += t.y;
                    t = up16(v.y); c1.x += t.x; c1.y += t.y;
                    t = up16(v.z); c2.x += t.x; c2.y += t.y;
                    t = up16(v.w); c3.x += t.x; c3.y += t.y;
                }
            }
            // reduce across the 8 edge slots (xor 8,16,32) — all lanes end with sum
#pragma unroll
            for (int m = 8; m < 64; m <<= 1) {
                c0.x += __shfl_xor(c0.x, m, 64); c0.y += __shfl_xor(c0.y, m, 64);
                c1.x += __shfl_xor(c1.x, m, 64); c1.y += __shfl_xor(c1.y, m, 64);
                c2.x += __shfl_xor(c2.x, m, 64); c2.y += __shfl_xor(c2.y, m, 64);
                c3.x += __shfl_xor(c3.x, m, 64); c3.y += __shfl_xor(c3.y, m, 64);
            }
            if (lane < 8) {  // lane == q8 here; add self row, pack, b128 LDS write
                const uint4 sv = xsu4[(size_t)n * 8 + lane];
                float2 t;
                uint4 w;
                t = up16(sv.x); w.x = pk16(c0.x + t.x, c0.y + t.y);
                t = up16(sv.y); w.y = pk16(c1.x + t.x, c1.y + t.y);
                t = up16(sv.z); w.z = pk16(c2.x + t.x, c2.y + t.y);
                t = up16(sv.w); w.w = pk16(c3.x + t.x, c3.y + t.y);
                ((uint4*)aggp[wid][i])[lane] = w;  // pairs 4*lane..4*lane+3
            }
        }
        const float dvA = dinv[base];
        const float dvB = dinv[base + 1];
        // ============ GEMM1 for both nodes; weights read once ============
        __half2 hA0 = hz, hA1 = hz, hB0 = hz, hB1 = hz;
        float gA0 = 0.f, gA1 = 0.f, gB0 = 0.f, gB1 = 0.f;
#pragma unroll
        for (int q = 0; q < 8; ++q) {
            const uint4 aqA = ((const uint4*)aggp[wid][0])[q];  // b128 broadcast
            const uint4 aqB = ((const uint4*)aggp[wid][1])[q];
#pragma unroll
            for (int j = 0; j < 4; ++j) {
                const uint32 avA = (j == 0) ? aqA.x : (j == 1) ? aqA.y : (j == 2) ? aqA.z : aqA.w;
                const uint32 avB = (j == 0) ? aqB.x : (j == 1) ? aqB.y : (j == 2) ? aqB.z : aqB.w;
                const uint2 wv = w1d[(q * 4 + j) * 64 + lane];  // b64, shared A/B
                hA0 = __hfma2(u2h(avA), u2h(wv.x), hA0);
                hA1 = __hfma2(u2h(avA), u2h(wv.y), hA1);
                hB0 = __hfma2(u2h(avB), u2h(wv.x), hB0);
                hB1 = __hfma2(u2h(avB), u2h(wv.y), hB1);
            }
            if (q & 1) {
                float2 p;
                p = __half22float2(hA0); gA0 += p.x + p.y; hA0 = hz;
                p = __half22float2(hA1); gA1 += p.x + p.y; hA1 = hz;
                p = __half22float2(hB0); gB0 += p.x + p.y; hB0 = hz;
                p = __half22float2(hB1); gB1 += p.x + p.y; hB1 = hz;
            }
        }
        // ============ LN + ReLU + repack u, per node ============
#pragma unroll
        for (int i = 0; i < 2; ++i) {
            const float dv = (i == 0) ? dvA : dvB;
            const float t0 = ((i == 0) ? gA0 : gB0) * dv + b1s[lane];
            const float t1 = ((i == 0) ? gA1 : gB1) * dv + b1s[lane + 64];
            float s = t0 + t1;
#pragma unroll
            for (int off = 32; off > 0; off >>= 1) s += __shfl_xor(s, off, 64);
            const float mu = s * (1.f / 128.f);
            const float d0 = t0 - mu, d1 = t1 - mu;
            float v = d0 * d0 + d1 * d1;
#pragma unroll
            for (int off = 32; off > 0; off >>= 1) v += __shfl_xor(v, off, 64);
            const float rstd = rsqrtf(v * (1.f / 128.f) + 1e-5f);
            const float u0 = fmaxf(d0 * rstd * lnws[lane] + lnbs[lane], 0.f);
            const float u1 = fmaxf(d1 * rstd * lnws[lane + 64] + lnbs[lane + 64], 0.f);
            const int praw = (int)pk16(u0, u1);  // lane m: (u[m], u[m+64])
            const int ia = __shfl(praw, (2 * lane) & 63, 64);
            const int ib = __shfl(praw, (2 * lane + 1) & 63, 64);
            const float2 fa = up16((uint32)ia), fb = up16((uint32)ib);
            const float ux = (lane < 32) ? fa.x : fa.y;  // u[2*lane]
            const float uy = (lane < 32) ? fb.x : fb.y;  // u[2*lane+1]
            usp[wid][i][lane] = pk16(ux, uy);
        }
        // ============ GEMM2 for both nodes; weights read once (b64) ============
        __half2 hA = hz, hB = hz;
        float fA = 0.f, fB = 0.f;
#pragma unroll
        for (int q = 0; q < 16; ++q) {
            const uint4 uqA = ((const uint4*)usp[wid][0])[q];  // b128 broadcast
            const uint4 uqB = ((const uint4*)usp[wid][1])[q];
            const uint2 wv0 = w2q[(2 * q) * 64 + lane];        // k 8q..8q+3
            const uint2 wv1 = w2q[(2 * q + 1) * 64 + lane];    // k 8q+4..8q+7
            hA = __hfma2(u2h(uqA.x), u2h(wv0.x), hA);
            hA = __hfma2(u2h(uqA.y), u2h(wv0.y), hA);
            hA = __hfma2(u2h(uqA.z), u2h(wv1.x), hA);
            hA = __hfma2(u2h(uqA.w), u2h(wv1.y), hA);
            hB = __hfma2(u2h(uqB.x), u2h(wv0.x), hB);
            hB = __hfma2(u2h(uqB.y), u2h(wv0.y), hB);
            hB = __hfma2(u2h(uqB.z), u2h(wv1.x), hB);
            hB = __hfma2(u2h(uqB.w), u2h(wv1.y), hB);
            if ((q & 3) == 3) {
                float2 p;
                p = __half22float2(hA); fA += p.x + p.y; hA = hz;
                p = __half22float2(hB); fB += p.x + p.y; hB = hz;
            }
        }
        // ============ store packed fp16 pairs, per node ============
#pragma unroll
        for (int i = 0; i < 2; ++i) {
            const float a2 = ((i == 0) ? fA : fB) * ((i == 0) ? dvA : dvB);
            const float e  = __shfl(a2, (2 * lane) & 63, 64);
            const float f2 = __shfl(a2, (2 * lane + 1) & 63, 64);
            if (lane < 32) a2u[(size_t)(base + i) * 32 + lane] = pk16(e, f2);
        }
    }
}

// ------ fused layer2: b128 gather (8 lanes/edge) + self + dinv + b2 → out ----------
__global__ __launch_bounds__(256) void k_gather2(
    const int* __restrict__ rowptr, const int* __restrict__ src,
    const uint32* __restrict__ a2u, const float* __restrict__ dinv,
    const void* __restrict__ b2, void* __restrict__ out,
    float* __restrict__ h2f, const int* __restrict__ flags) {
    const int F32 = flags[0];
    __shared__ float b2s[F_OUT];
    if (threadIdx.x < F_OUT) b2s[threadIdx.x] = ldF(b2, threadIdx.x, F32);
    __syncthreads();
    const int wid = threadIdx.x >> 6;
    const int lane = threadIdx.x & 63;
    const int g8 = lane >> 3;
    const int q8 = lane & 7;
    const uint4* __restrict__ a2u4 = (const uint4*)a2u;
    for (int n0 = blockIdx.x * 4 + wid; n0 < N_NODES; n0 += gridDim.x * 4) {
        const int n = __builtin_amdgcn_readfirstlane(n0);
        const int beg = rowptr[n], end = rowptr[n + 1];
        float2 c0 = {0.f, 0.f}, c1 = {0.f, 0.f}, c2 = {0.f, 0.f}, c3 = {0.f, 0.f};
        int pe = beg + g8;
        int pidx = (pe < end) ? src[pe] : -1;
        for (int jj = beg; jj < end; jj += 8) {
            const int idx = pidx;
            const int ne = jj + 8 + g8;
            pidx = (ne < end) ? src[ne] : -1;
            if (idx >= 0) {
                const uint4 v = a2u4[(size_t)idx * 8 + q8];
                float2 t;
                t = up16(v.x); c0.x += t.x; c0.y += t.y;
                t = up16(v.y); c1.x += t.x; c1.y += t.y;
                t = up16(v.z); c2.x += t.x; c2.y += t.y;
                t = up16(v.w); c3.x += t.x; c3.y += t.y;
            }
        }
#pragma unroll
        for (int m = 8; m < 64; m <<= 1) {
            c0.x += __shfl_xor(c0.x, m, 64); c0.y += __shfl_xor(c0.y, m, 64);
            c1.x += __shfl_xor(c1.x, m, 64); c1.y += __shfl_xor(c1.y, m, 64);
            c2.x += __shfl_xor(c2.x, m, 64); c2.y += __shfl_xor(c2.y, m, 64);
            c3.x += __shfl_xor(c3.x, m, 64); c3.y += __shfl_xor(c3.y, m, 64);
        }
        if (lane < 8) {  // lane == q8; feats 8*lane .. 8*lane+7
            const uint4 sv = a2u4[(size_t)n * 8 + lane];
            const float dv = dinv[n];
            float2 t;
            t = up16(sv.x);
            const float r0 = (c0.x + t.x) * dv + b2s[8 * lane + 0];
            const float r1 = (c0.y + t.y) * dv + b2s[8 * lane + 1];
            t = up16(sv.y);
            const float r2 = (c1.x + t.x) * dv + b2s[8 * lane + 2];
            const float r3 = (c1.y + t.y) * dv + b2s[8 * lane + 3];
            t = up16(sv.z);
            const float r4 = (c2.x + t.x) * dv + b2s[8 * lane + 4];
            const float r5 = (c2.y + t.y) * dv + b2s[8 * lane + 5];
            t = up16(sv.w);
            const float r6 = (c3.x + t.x) * dv + b2s[8 * lane + 6];
            const float r7 = (c3.y + t.y) * dv + b2s[8 * lane + 7];
            float4 w0; w0.x = r0; w0.y = r1; w0.z = r2; w0.w = r3;
            float4 w1; w1.x = r4; w1.y = r5; w1.z = r6; w1.w = r7;
            ((float4*)h2f)[(size_t)n * 16 + lane * 2] = w0;      // fp32 keep for pooling
            ((float4*)h2f)[(size_t)n * 16 + lane * 2 + 1] = w1;
            if (F32) {
                ((float4*)out)[(size_t)n * 16 + lane * 2] = w0;
                ((float4*)out)[(size_t)n * 16 + lane * 2 + 1] = w1;
            } else {
                uint4 ub;
                ub.x = ((uint32)bfbits(r1) << 16) | (uint32)bfbits(r0);
                ub.y = ((uint32)bfbits(r3) << 16) | (uint32)bfbits(r2);
                ub.z = ((uint32)bfbits(r5) << 16) | (uint32)bfbits(r4);
                ub.w = ((uint32)bfbits(r7) << 16) | (uint32)bfbits(r6);
                ((uint4*)out)[(size_t)n * 8 + lane] = ub;
            }
        }
    }
}

// ---------------- per-graph counts via binary search on sorted batch ---------------
__global__ void k_counts(const void* __restrict__ batch, int* __restrict__ counts,
                         const int* __restrict__ flags) {
    const int i64 = flags[1];
    int g = threadIdx.x;
    if (g < N_GRAPHS) {
        int lo = 0, hi = N_NODES;
        while (lo < hi) { int m = (lo + hi) >> 1; if (ldI(batch, m, i64) < g) lo = m + 1; else hi = m; }
        int lb = lo;
        lo = 0; hi = N_NODES;
        while (lo < hi) { int m = (lo + hi) >> 1; if (ldI(batch, m, i64) <= g) lo = m + 1; else hi = m; }
        counts[g] = lo - lb;
    }
}

// ---------------- pooling: segmented per-wave reduction (batch sorted) -------------
__global__ __launch_bounds__(256) void k_pool(const float* __restrict__ h2,
                                              const void* __restrict__ batch,
                                              float* __restrict__ gsum,
                                              const int* __restrict__ flags) {
    const int i64 = flags[1];
    const int wid = (blockIdx.x * blockDim.x + threadIdx.x) >> 6;
    const int lane = threadIdx.x & 63;
    const int nwaves = (gridDim.x * blockDim.x) >> 6;
    const int per = (N_NODES + nwaves - 1) / nwaves;
    const int start = wid * per;
    const int end = min(start + per, N_NODES);
    if (start >= end) return;
    float acc = 0.f;
    int gcur = ldI(batch, start, i64);
    for (int n = start; n < end; ++n) {
        int g = ldI(batch, n, i64);
        if (g != gcur) {
            atomicAdd(&gsum[gcur * 64 + lane], acc);
            acc = 0.f;
            gcur = g;
        }
        acc += h2[(size_t)n * 64 + lane];
    }
    atomicAdd(&gsum[gcur * 64 + lane], acc);
}

__global__ void k_gout(const float* __restrict__ gsum, const int* __restrict__ counts,
                       void* __restrict__ out, const int* __restrict__ flags) {
    const int F32 = flags[0];
    int idx = blockIdx.x * blockDim.x + threadIdx.x;
    if (idx < N_GRAPHS * 64) {
        int g = idx >> 6;
        float c = (float)max(counts[g], 1);
        stF(out, (size_t)N_NODES * F_OUT + idx, gsum[idx] / c, F32);
    }
}

extern "C" void kernel_launch(void* const* d_in, const int* in_sizes, int n_in,
                              void* d_out, int out_size, void* d_ws, size_t ws_size,
                              hipStream_t stream) {
    const void* x   = d_in[0];
    const void* ei  = d_in[1];
    const void* bat = d_in[2];
    const void* W1  = d_in[3];
    const void* b1  = d_in[4];
    const void* lnw = d_in[5];
    const void* lnb = d_in[6];
    const void* W2  = d_in[7];
    const void* b2  = d_in[8];

    char* ws = (char*)d_ws;
    size_t o = 0;
    auto alloc = [&](size_t bytes) { size_t r = o; o += (bytes + 255) & ~(size_t)255; return r; };
    int*    flags  = (int*)   (ws + alloc(2 * 4));
    float*  dinv   = (float*) (ws + alloc((size_t)N_NODES * 4));
    int*    deg    = (int*)   (ws + alloc((size_t)N_NODES * 4));
    int*    rowptr = (int*)   (ws + alloc((size_t)(N_NODES + 1) * 4));
    int*    cursor = (int*)   (ws + alloc((size_t)N_NODES * 4));
    int*    bsum   = (int*)   (ws + alloc((size_t)NB_SCAN * 4));
    int*    bbase  = (int*)   (ws + alloc((size_t)NB_SCAN * 4));
    int*    srcidx = (int*)   (ws + alloc((size_t)N_EDGES * 4));
    uint32* xs16   = (uint32*)(ws + alloc((size_t)N_NODES * 32 * 4));
    uint32* a2u    = (uint32*)(ws + alloc((size_t)N_NODES * 32 * 4));
    float*  h2f    = (float*) (ws + alloc((size_t)N_NODES * F_OUT * 4));
    float*  gsum   = (float*) (ws + alloc((size_t)N_GRAPHS * 64 * 4));
    int*    counts = (int*)   (ws + alloc((size_t)N_GRAPHS * 4));

    hipMemsetAsync(deg, 0, (size_t)N_NODES * 4, stream);
    hipMemsetAsync(gsum, 0, (size_t)N_GRAPHS * 64 * 4, stream);

    GCNEncoder_77214922048129_kernel<<<1, 256, 0, stream>>>(x, ei, flags);
    k_deg<<<(N_EDGES + 255) / 256, 256, 0, stream>>>(ei, deg, flags);
    k_dinv<<<(N_NODES + 255) / 256, 256, 0, stream>>>(deg, dinv);
    k_bsum<<<NB_SCAN, 256, 0, stream>>>(deg, bsum);
    k_bscan<<<1, 512, 0, stream>>>(bsum, bbase);
    k_rowptr<<<NB_SCAN, 256, 0, stream>>>(deg, bbase, rowptr, cursor);
    k_csr<<<(N_EDGES + 255) / 256, 256, 0, stream>>>(ei, cursor, srcidx, flags);
    k_scale<<<(N_NODES * 32 + 255) / 256, 256, 0, stream>>>(x, dinv, xs16, flags);
    k_gather1<<<2048, 64 * G1W, 0, stream>>>(rowptr, srcidx, xs16, dinv, b1, lnw, lnb,
                                             W1, W2, a2u, flags);
    k_gather2<<<4096, 256, 0, stream>>>(rowptr, srcidx, a2u, dinv, b2, d_out, h2f, flags);
    k_counts<<<1, 64, 0, stream>>>(bat, counts, flags);
    k_pool<<<512, 256, 0, stream>>>(h2f, bat, gsum, flags);
    k_gout<<<(N_GRAPHS * 64 + 255) / 256, 256, 0, stream>>>(gsum, counts, d_out, flags);
}

// Round 11
// 538.242 us; speedup vs baseline: 1.0705x; 1.0705x over previous
//
#include <hip/hip_runtime.h>
#include <hip/hip_bf16.h>
#include <hip/hip_fp16.h>
#include <cstdint>

#define N_NODES 100000
#define N_EDGES 1600000
#define N_GRAPHS 64
#define F_IN 64
#define F_MID 128
#define F_OUT 64

typedef unsigned int uint32;

// ---- dtype-agnostic accessors (flags[0]=1 → floats are fp32; flags[1]=1 → ints are int64)
__device__ __forceinline__ float ldF(const void* p, size_t i, int f32) {
    return f32 ? ((const float*)p)[i]
               : __bfloat162float(((const __hip_bfloat16*)p)[i]);
}
__device__ __forceinline__ int ldI(const void* p, size_t i, int i64) {
    return i64 ? (int)((const long long*)p)[i] : ((const int*)p)[i];
}
__device__ __forceinline__ void stF(void* p, size_t i, float v, int f32) {
    if (f32) ((float*)p)[i] = v;
    else     ((__hip_bfloat16*)p)[i] = __float2bfloat16(v);
}

// ---- fp16x2 pack/unpack (SCALAR unions only — arrays of unions spill to scratch!) ----
union H2U { uint32 u; __half2 h; };
__device__ __forceinline__ float2 up16(uint32 u) {
    H2U c; c.u = u;
    return __half22float2(c.h);
}
__device__ __forceinline__ __half2 u2h(uint32 u) {
    H2U c; c.u = u;
    return c.h;
}
__device__ __forceinline__ uint32 pk16(float a, float b) {
    H2U c; c.h = __floats2half2_rn(a, b);
    return c.u;
}
__device__ __forceinline__ unsigned short bfbits(float f) {
    __hip_bfloat16 b = __float2bfloat16(f);
    return *(unsigned short*)&b;
}

// ---------------- dtype sniffer ----------------------------------------------------
__global__ void GCNEncoder_77214922048129_kernel(const void* x, const void* ei,
                                                 int* flags) {
    __shared__ int cnt_weird, cnt_zero;
    if (threadIdx.x == 0) { cnt_weird = 0; cnt_zero = 0; }
    __syncthreads();
    const unsigned short* u = (const unsigned short*)x;
    int w = 0;
    for (int i = threadIdx.x; i < 2048; i += 256) {
        int e = (u[i] >> 7) & 0xFF;
        if (e == 0xFF || e >= 159 || (e > 0 && e <= 95)) w++;
    }
    atomicAdd(&cnt_weird, w);
    const int* ii = (const int*)ei;
    int z = 0;
    for (int i = threadIdx.x; i < 128; i += 256) {
        if (ii[2 * i + 1] == 0) z++;
    }
    atomicAdd(&cnt_zero, z);
    __syncthreads();
    if (threadIdx.x == 0) {
        flags[0] = (cnt_weird > 64) ? 1 : 0;  // fp32 floats
        flags[1] = (cnt_zero > 64) ? 1 : 0;   // int64 indices
    }
}

// ---------------- degree over col (self-loop added analytically) -------------------
__global__ void k_deg(const void* __restrict__ ei, int* __restrict__ deg,
                      const int* __restrict__ flags) {
    const int i64 = flags[1];
    int e = blockIdx.x * blockDim.x + threadIdx.x;
    if (e < N_EDGES) atomicAdd(&deg[ldI(ei, (size_t)N_EDGES + e, i64)], 1);
}

// ---------------- CSR build: 3-stage parallel exclusive scan of deg ----------------
#define NB_SCAN ((N_NODES + 255) / 256)  // 391

// fused: block-sum for scan + dinv computation
__global__ __launch_bounds__(256) void k_bsum(const int* __restrict__ deg,
                                              int* __restrict__ bsum,
                                              float* __restrict__ dinv) {
    __shared__ int sh[256];
    int idx = blockIdx.x * 256 + threadIdx.x;
    int d = 0;
    if (idx < N_NODES) {
        d = deg[idx];
        dinv[idx] = rsqrtf((float)d + 1.0f);  // +1 = self-loop
    }
    sh[threadIdx.x] = d;
    __syncthreads();
#pragma unroll
    for (int off = 128; off > 0; off >>= 1) {
        if (threadIdx.x < off) sh[threadIdx.x] += sh[threadIdx.x + off];
        __syncthreads();
    }
    if (threadIdx.x == 0) bsum[blockIdx.x] = sh[0];
}

__global__ __launch_bounds__(512) void k_bscan(const int* __restrict__ bsum,
                                               int* __restrict__ bbase) {
    __shared__ int sh[512];
    const int t = threadIdx.x;
    sh[t] = (t < NB_SCAN) ? bsum[t] : 0;
    __syncthreads();
    for (int off = 1; off < 512; off <<= 1) {
        int v = (t >= off) ? sh[t - off] : 0;
        __syncthreads();
        sh[t] += v;
        __syncthreads();
    }
    if (t < NB_SCAN) bbase[t] = (t == 0) ? 0 : sh[t - 1];
}

__global__ __launch_bounds__(256) void k_rowptr(const int* __restrict__ deg,
                                                const int* __restrict__ bbase,
                                                int* __restrict__ rowptr,
                                                int* __restrict__ cursor) {
    __shared__ int sh[256];
    const int t = threadIdx.x;
    const int idx = blockIdx.x * 256 + t;
    const int d = (idx < N_NODES) ? deg[idx] : 0;
    sh[t] = d;
    __syncthreads();
    for (int off = 1; off < 256; off <<= 1) {
        int v = (t >= off) ? sh[t - off] : 0;
        __syncthreads();
        sh[t] += v;
        __syncthreads();
    }
    if (idx < N_NODES) {
        int r = bbase[blockIdx.x] + sh[t] - d;  // exclusive
        rowptr[idx] = r;
        cursor[idx] = r;
    }
    if (idx == 0) rowptr[N_NODES] = N_EDGES;
}

// ---------------- CSR scatter: src[pos(c)] = r -------------------------------------
__global__ __launch_bounds__(256) void k_csr(const void* __restrict__ ei,
                                             int* __restrict__ cursor,
                                             int* __restrict__ src,
                                             const int* __restrict__ flags) {
    const int i64 = flags[1];
    int e = blockIdx.x * blockDim.x + threadIdx.x;
    if (e < N_EDGES) {
        int r = ldI(ei, e, i64);
        int c = ldI(ei, (size_t)N_EDGES + e, i64);
        int pos = atomicAdd(&cursor[c], 1);
        src[pos] = r;
    }
}

// ---------------- xs16[n] = fp16( x[n] * dinv[n] ), packed pairs -------------------
__global__ __launch_bounds__(256) void k_scale(const void* __restrict__ x,
                                               const float* __restrict__ dinv,
                                               uint32* __restrict__ xs16,
                                               const int* __restrict__ flags) {
    const int F32 = flags[0];
    int idx = blockIdx.x * blockDim.x + threadIdx.x;  // feature-pair index
    if (idx < N_NODES * 32) {
        int n = idx >> 5;
        float dv = dinv[n];
        float a = ldF(x, (size_t)idx * 2, F32) * dv;
        float b = ldF(x, (size_t)idx * 2 + 1, F32) * dv;
        xs16[idx] = pk16(a, b);
    }
}

// ------ fused layer1: dual-chunk gather + GEMM1 + LN + ReLU + GEMM2 (hfma2) --------
// ONE node per wave (r8 structure, low VGPR). Gather main loop covers 16 edges with
// all indices s_loaded upfront → 8 concurrent row-loads per lane-half, ONE latency.
#define G1W 8
__global__ __launch_bounds__(64 * G1W) void k_gather1(
    const int* __restrict__ rowptr, const int* __restrict__ src,
    const uint32* __restrict__ xsu, const float* __restrict__ dinv,
    const void* __restrict__ b1, const void* __restrict__ lnw,
    const void* __restrict__ lnb, const void* __restrict__ W1,
    const void* __restrict__ W2, uint32* __restrict__ a2u,
    const int* __restrict__ flags) {
    const int F32 = flags[0];
    __shared__ uint2  w1d[32 * 64];   // [k2][f]: .x=(W1[2k2][f],W1[2k2+1][f]) .y=@f+64 ; 16 KB
    __shared__ uint2  w2q[32 * 64];   // [k4][f]: 4 k-values of W2 per entry ; 16 KB
    __shared__ float b1s[F_MID], lnws[F_MID], lnbs[F_MID];
    __shared__ uint32 aggp[G1W][32];  // packed agg k-pairs per wave
    __shared__ uint32 usp[G1W][64];   // packed u k-pairs per wave
    for (int i = threadIdx.x; i < 32 * 64; i += 64 * G1W) {
        const int k2 = i >> 6, f = i & 63;
        uint2 w;
        w.x = pk16(ldF(W1, (size_t)(2 * k2) * F_MID + f, F32),
                   ldF(W1, (size_t)(2 * k2 + 1) * F_MID + f, F32));
        w.y = pk16(ldF(W1, (size_t)(2 * k2) * F_MID + f + 64, F32),
                   ldF(W1, (size_t)(2 * k2 + 1) * F_MID + f + 64, F32));
        w1d[i] = w;
    }
    for (int i = threadIdx.x; i < 32 * 64; i += 64 * G1W) {
        const int k4 = i >> 6, f = i & 63;
        uint2 w;
        w.x = pk16(ldF(W2, (size_t)(4 * k4) * F_OUT + f, F32),
                   ldF(W2, (size_t)(4 * k4 + 1) * F_OUT + f, F32));
        w.y = pk16(ldF(W2, (size_t)(4 * k4 + 2) * F_OUT + f, F32),
                   ldF(W2, (size_t)(4 * k4 + 3) * F_OUT + f, F32));
        w2q[i] = w;
    }
    if (threadIdx.x < F_MID) {
        b1s[threadIdx.x] = ldF(b1, threadIdx.x, F32);
        lnws[threadIdx.x] = ldF(lnw, threadIdx.x, F32);
        lnbs[threadIdx.x] = ldF(lnb, threadIdx.x, F32);
    }
    __syncthreads();
    const int wid = threadIdx.x >> 6;
    const int lane = threadIdx.x & 63;
    const int h = lane >> 5;    // which edge of the pair
    const int fp = lane & 31;   // feature-pair index
    const __half2 hz = __float2half2_rn(0.f);
    for (int n0 = blockIdx.x * G1W + wid; n0 < N_NODES; n0 += gridDim.x * G1W) {
        const int n = __builtin_amdgcn_readfirstlane(n0);
        const int beg = rowptr[n], end = rowptr[n + 1];
        float2 a0 = {0.f, 0.f}, a1 = {0.f, 0.f};
        int jj = beg;
        // ---- main: 16 edges, all idx up-front → 8 concurrent row-loads/lane ----
        for (; jj + 16 <= end; jj += 16) {
            const int p0 = src[jj], p1 = src[jj + 1], p2 = src[jj + 2], p3 = src[jj + 3];
            const int p4 = src[jj + 4], p5 = src[jj + 5], p6 = src[jj + 6], p7 = src[jj + 7];
            const int p8 = src[jj + 8], p9 = src[jj + 9], pa = src[jj + 10], pb = src[jj + 11];
            const int pc = src[jj + 12], pd = src[jj + 13], pe = src[jj + 14], pf = src[jj + 15];
            const int iA = h ? p1 : p0, iB = h ? p3 : p2, iC = h ? p5 : p4, iD = h ? p7 : p6;
            const int iE = h ? p9 : p8, iF = h ? pb : pa, iG = h ? pd : pc, iH = h ? pf : pe;
            const float2 vA = up16(xsu[(size_t)iA * 32 + fp]);
            const float2 vB = up16(xsu[(size_t)iB * 32 + fp]);
            const float2 vC = up16(xsu[(size_t)iC * 32 + fp]);
            const float2 vD = up16(xsu[(size_t)iD * 32 + fp]);
            const float2 vE = up16(xsu[(size_t)iE * 32 + fp]);
            const float2 vF = up16(xsu[(size_t)iF * 32 + fp]);
            const float2 vG = up16(xsu[(size_t)iG * 32 + fp]);
            const float2 vH = up16(xsu[(size_t)iH * 32 + fp]);
            a0.x += (vA.x + vC.x) + (vE.x + vG.x);
            a0.y += (vA.y + vC.y) + (vE.y + vG.y);
            a1.x += (vB.x + vD.x) + (vF.x + vH.x);
            a1.y += (vB.y + vD.y) + (vF.y + vH.y);
        }
        for (; jj + 8 <= end; jj += 8) {
            const int p0 = src[jj], p1 = src[jj + 1], p2 = src[jj + 2], p3 = src[jj + 3];
            const int p4 = src[jj + 4], p5 = src[jj + 5], p6 = src[jj + 6], p7 = src[jj + 7];
            const int iA = h ? p1 : p0, iB = h ? p3 : p2, iC = h ? p5 : p4, iD = h ? p7 : p6;
            const float2 vA = up16(xsu[(size_t)iA * 32 + fp]);
            const float2 vB = up16(xsu[(size_t)iB * 32 + fp]);
            const float2 vC = up16(xsu[(size_t)iC * 32 + fp]);
            const float2 vD = up16(xsu[(size_t)iD * 32 + fp]);
            a0.x += vA.x + vC.x; a0.y += vA.y + vC.y;
            a1.x += vB.x + vD.x; a1.y += vB.y + vD.y;
        }
        for (; jj < end; jj += 2) {
            const int i0 = src[jj];
            const int i1 = (jj + 1 < end) ? src[jj + 1] : -1;
            const int ix = h ? i1 : i0;
            if (ix >= 0) {
                const float2 v = up16(xsu[(size_t)ix * 32 + fp]);
                a0.x += v.x; a0.y += v.y;
            }
        }
        float sx = a0.x + a1.x, sy = a0.y + a1.y;
        sx += __shfl_xor(sx, 32, 64);
        sy += __shfl_xor(sy, 32, 64);
        const float2 sv = up16(xsu[(size_t)n * 32 + fp]);  // self (already * dinv)
        sx += sv.x; sy += sv.y;
        if (h == 0) aggp[wid][fp] = pk16(sx, sy);  // within-wave RAW (lgkmcnt wait)
        const float dv = dinv[n];
        // ---- GEMM1: lane f handles f and f+64; hfma2, promote every 16 k ----
        __half2 hc0 = hz, hc1 = hz;
        float g0 = 0.f, g1 = 0.f;
#pragma unroll
        for (int q = 0; q < 8; ++q) {
            const uint4 aq = ((const uint4*)aggp[wid])[q];  // b128 broadcast
#pragma unroll
            for (int j = 0; j < 4; ++j) {
                const uint32 av = (j == 0) ? aq.x : (j == 1) ? aq.y : (j == 2) ? aq.z : aq.w;
                const uint2 wv = w1d[(q * 4 + j) * 64 + lane];
                hc0 = __hfma2(u2h(av), u2h(wv.x), hc0);
                hc1 = __hfma2(u2h(av), u2h(wv.y), hc1);
            }
            if (q & 1) {
                float2 p;
                p = __half22float2(hc0); g0 += p.x + p.y; hc0 = hz;
                p = __half22float2(hc1); g1 += p.x + p.y; hc1 = hz;
            }
        }
        const float t0 = g0 * dv + b1s[lane];
        const float t1 = g1 * dv + b1s[lane + 64];
        // ---- LayerNorm over 128 ----
        float s = t0 + t1;
#pragma unroll
        for (int off = 32; off > 0; off >>= 1) s += __shfl_xor(s, off, 64);
        const float mu = s * (1.f / 128.f);
        const float d0 = t0 - mu, d1 = t1 - mu;
        float v = d0 * d0 + d1 * d1;
#pragma unroll
        for (int off = 32; off > 0; off >>= 1) v += __shfl_xor(v, off, 64);
        const float rstd = rsqrtf(v * (1.f / 128.f) + 1e-5f);
        const float u0 = fmaxf(d0 * rstd * lnws[lane] + lnbs[lane], 0.f);
        const float u1 = fmaxf(d1 * rstd * lnws[lane + 64] + lnbs[lane + 64], 0.f);
        // repack u into k-pair layout: usp[k2] = (u[2k2], u[2k2+1])
        const int praw = (int)pk16(u0, u1);  // lane m: (u[m], u[m+64])
        const int ia = __shfl(praw, (2 * lane) & 63, 64);
        const int ib = __shfl(praw, (2 * lane + 1) & 63, 64);
        const float2 fa = up16((uint32)ia), fb = up16((uint32)ib);
        const float ux = (lane < 32) ? fa.x : fa.y;  // u[2*lane]
        const float uy = (lane < 32) ? fb.x : fb.y;  // u[2*lane+1]
        usp[wid][lane] = pk16(ux, uy);
        // ---- GEMM2: a2[lane] = (u @ W2)[lane] * dv ; b64 weights, promote /32k ----
        __half2 hc = hz;
        float facc = 0.f;
#pragma unroll
        for (int q = 0; q < 16; ++q) {
            const uint4 uq = ((const uint4*)usp[wid])[q];  // b128 broadcast
            const uint2 wv0 = w2q[(2 * q) * 64 + lane];    // k 8q..8q+3
            const uint2 wv1 = w2q[(2 * q + 1) * 64 + lane];// k 8q+4..8q+7
            hc = __hfma2(u2h(uq.x), u2h(wv0.x), hc);
            hc = __hfma2(u2h(uq.y), u2h(wv0.y), hc);
            hc = __hfma2(u2h(uq.z), u2h(wv1.x), hc);
            hc = __hfma2(u2h(uq.w), u2h(wv1.y), hc);
            if ((q & 3) == 3) {
                const float2 p = __half22float2(hc);
                facc += p.x + p.y;
                hc = hz;
            }
        }
        const float a2 = facc * dv;
        // ---- store packed fp16 pairs ----
        const float e  = __shfl(a2, (2 * lane) & 63, 64);
        const float f2 = __shfl(a2, (2 * lane + 1) & 63, 64);
        if (lane < 32) a2u[(size_t)n * 32 + lane] = pk16(e, f2);
    }
}

// ------ fused layer2: dual-chunk fp16 gather + self + dinv + b2 → out --------------
__global__ __launch_bounds__(256) void k_gather2(
    const int* __restrict__ rowptr, const int* __restrict__ src,
    const uint32* __restrict__ a2u, const float* __restrict__ dinv,
    const void* __restrict__ b2, void* __restrict__ out,
    const int* __restrict__ flags) {
    const int F32 = flags[0];
    __shared__ float b2s[F_OUT];
    if (threadIdx.x < F_OUT) b2s[threadIdx.x] = ldF(b2, threadIdx.x, F32);
    __syncthreads();
    const int wid = threadIdx.x >> 6;
    const int lane = threadIdx.x & 63;
    const int h = lane >> 5;
    const int fp = lane & 31;
    for (int n0 = blockIdx.x * 4 + wid; n0 < N_NODES; n0 += gridDim.x * 4) {
        const int n = __builtin_amdgcn_readfirstlane(n0);
        const int beg = rowptr[n], end = rowptr[n + 1];
        float2 a0 = {0.f, 0.f}, a1 = {0.f, 0.f};
        int jj = beg;
        for (; jj + 16 <= end; jj += 16) {
            const int p0 = src[jj], p1 = src[jj + 1], p2 = src[jj + 2], p3 = src[jj + 3];
            const int p4 = src[jj + 4], p5 = src[jj + 5], p6 = src[jj + 6], p7 = src[jj + 7];
            const int p8 = src[jj + 8], p9 = src[jj + 9], pa = src[jj + 10], pb = src[jj + 11];
            const int pc = src[jj + 12], pd = src[jj + 13], pe = src[jj + 14], pf = src[jj + 15];
            const int iA = h ? p1 : p0, iB = h ? p3 : p2, iC = h ? p5 : p4, iD = h ? p7 : p6;
            const int iE = h ? p9 : p8, iF = h ? pb : pa, iG = h ? pd : pc, iH = h ? pf : pe;
            const float2 vA = up16(a2u[(size_t)iA * 32 + fp]);
            const float2 vB = up16(a2u[(size_t)iB * 32 + fp]);
            const float2 vC = up16(a2u[(size_t)iC * 32 + fp]);
            const float2 vD = up16(a2u[(size_t)iD * 32 + fp]);
            const float2 vE = up16(a2u[(size_t)iE * 32 + fp]);
            const float2 vF = up16(a2u[(size_t)iF * 32 + fp]);
            const float2 vG = up16(a2u[(size_t)iG * 32 + fp]);
            const float2 vH = up16(a2u[(size_t)iH * 32 + fp]);
            a0.x += (vA.x + vC.x) + (vE.x + vG.x);
            a0.y += (vA.y + vC.y) + (vE.y + vG.y);
            a1.x += (vB.x + vD.x) + (vF.x + vH.x);
            a1.y += (vB.y + vD.y) + (vF.y + vH.y);
        }
        for (; jj + 8 <= end; jj += 8) {
            const int p0 = src[jj], p1 = src[jj + 1], p2 = src[jj + 2], p3 = src[jj + 3];
            const int p4 = src[jj + 4], p5 = src[jj + 5], p6 = src[jj + 6], p7 = src[jj + 7];
            const int iA = h ? p1 : p0, iB = h ? p3 : p2, iC = h ? p5 : p4, iD = h ? p7 : p6;
            const float2 vA = up16(a2u[(size_t)iA * 32 + fp]);
            const float2 vB = up16(a2u[(size_t)iB * 32 + fp]);
            const float2 vC = up16(a2u[(size_t)iC * 32 + fp]);
            const float2 vD = up16(a2u[(size_t)iD * 32 + fp]);
            a0.x += vA.x + vC.x; a0.y += vA.y + vC.y;
            a1.x += vB.x + vD.x; a1.y += vB.y + vD.y;
        }
        for (; jj < end; jj += 2) {
            const int i0 = src[jj];
            const int i1 = (jj + 1 < end) ? src[jj + 1] : -1;
            const int ix = h ? i1 : i0;
            if (ix >= 0) {
                const float2 v = up16(a2u[(size_t)ix * 32 + fp]);
                a0.x += v.x; a0.y += v.y;
            }
        }
        float sx = a0.x + a1.x, sy = a0.y + a1.y;
        sx += __shfl_xor(sx, 32, 64);
        sy += __shfl_xor(sy, 32, 64);
        const float2 sv = up16(a2u[(size_t)n * 32 + fp]);  // self term
        const float dv = dinv[n];
        const float2 b2v = ((const float2*)b2s)[fp];
        float2 r;
        r.x = (sx + sv.x) * dv + b2v.x;
        r.y = (sy + sv.y) * dv + b2v.y;
        if (h == 0) {
            if (F32) {
                ((float2*)out)[(size_t)n * 32 + fp] = r;
            } else {
                uint32 ub = ((uint32)bfbits(r.y) << 16) | (uint32)bfbits(r.x);
                ((uint32*)out)[(size_t)n * 32 + fp] = ub;
            }
        }
    }
}

// ---------------- pooling: segmented per-wave reduction (reads d_out h) ------------
__global__ __launch_bounds__(256) void k_pool(const void* __restrict__ hout,
                                              const void* __restrict__ batch,
                                              float* __restrict__ gsum,
                                              const int* __restrict__ flags) {
    const int F32 = flags[0];
    const int i64 = flags[1];
    const int wid = (blockIdx.x * blockDim.x + threadIdx.x) >> 6;
    const int lane = threadIdx.x & 63;
    const int nwaves = (gridDim.x * blockDim.x) >> 6;
    const int per = (N_NODES + nwaves - 1) / nwaves;
    const int start = wid * per;
    const int end = min(start + per, N_NODES);
    if (start >= end) return;
    float acc = 0.f;
    int gcur = ldI(batch, start, i64);
    for (int n = start; n < end; ++n) {
        int g = ldI(batch, n, i64);
        if (g != gcur) {
            atomicAdd(&gsum[gcur * 64 + lane], acc);
            acc = 0.f;
            gcur = g;
        }
        acc += ldF(hout, (size_t)n * 64 + lane, F32);
    }
    atomicAdd(&gsum[gcur * 64 + lane], acc);
}

// ---------------- g-output with inline per-graph count (binary search) -------------
__global__ void k_gout(const float* __restrict__ gsum, const void* __restrict__ batch,
                       void* __restrict__ out, const int* __restrict__ flags) {
    const int F32 = flags[0];
    const int i64 = flags[1];
    int idx = blockIdx.x * blockDim.x + threadIdx.x;
    if (idx < N_GRAPHS * 64) {
        int g = idx >> 6;  // wave-uniform within 64-thread groups
        int lo = 0, hi = N_NODES;
        while (lo < hi) { int m = (lo + hi) >> 1; if (ldI(batch, m, i64) < g) lo = m + 1; else hi = m; }
        int lb = lo;
        lo = 0; hi = N_NODES;
        while (lo < hi) { int m = (lo + hi) >> 1; if (ldI(batch, m, i64) <= g) lo = m + 1; else hi = m; }
        float c = (float)max(lo - lb, 1);
        stF(out, (size_t)N_NODES * F_OUT + idx, gsum[idx] / c, F32);
    }
}

extern "C" void kernel_launch(void* const* d_in, const int* in_sizes, int n_in,
                              void* d_out, int out_size, void* d_ws, size_t ws_size,
                              hipStream_t stream) {
    const void* x   = d_in[0];
    const void* ei  = d_in[1];
    const void* bat = d_in[2];
    const void* W1  = d_in[3];
    const void* b1  = d_in[4];
    const void* lnw = d_in[5];
    const void* lnb = d_in[6];
    const void* W2  = d_in[7];
    const void* b2  = d_in[8];

    char* ws = (char*)d_ws;
    size_t o = 0;
    auto alloc = [&](size_t bytes) { size_t r = o; o += (bytes + 255) & ~(size_t)255; return r; };
    int*    flags  = (int*)   (ws + alloc(2 * 4));
    float*  dinv   = (float*) (ws + alloc((size_t)N_NODES * 4));
    int*    deg    = (int*)   (ws + alloc((size_t)N_NODES * 4));
    int*    rowptr = (int*)   (ws + alloc((size_t)(N_NODES + 1) * 4));
    int*    cursor = (int*)   (ws + alloc((size_t)N_NODES * 4));
    int*    bsum   = (int*)   (ws + alloc((size_t)NB_SCAN * 4));
    int*    bbase  = (int*)   (ws + alloc((size_t)NB_SCAN * 4));
    int*    srcidx = (int*)   (ws + alloc((size_t)N_EDGES * 4));
    uint32* xs16   = (uint32*)(ws + alloc((size_t)N_NODES * 32 * 4));
    uint32* a2u    = (uint32*)(ws + alloc((size_t)N_NODES * 32 * 4));
    float*  gsum   = (float*) (ws + alloc((size_t)N_GRAPHS * 64 * 4));

    hipMemsetAsync(deg, 0, (size_t)N_NODES * 4, stream);
    hipMemsetAsync(gsum, 0, (size_t)N_GRAPHS * 64 * 4, stream);

    GCNEncoder_77214922048129_kernel<<<1, 256, 0, stream>>>(x, ei, flags);
    k_deg<<<(N_EDGES + 255) / 256, 256, 0, stream>>>(ei, deg, flags);
    k_bsum<<<NB_SCAN, 256, 0, stream>>>(deg, bsum, dinv);
    k_bscan<<<1, 512, 0, stream>>>(bsum, bbase);
    k_rowptr<<<NB_SCAN, 256, 0, stream>>>(deg, bbase, rowptr, cursor);
    k_csr<<<(N_EDGES + 255) / 256, 256, 0, stream>>>(ei, cursor, srcidx, flags);
    k_scale<<<(N_NODES * 32 + 255) / 256, 256, 0, stream>>>(x, dinv, xs16, flags);
    k_gather1<<<512, 64 * G1W, 0, stream>>>(rowptr, srcidx, xs16, dinv, b1, lnw, lnb,
                                            W1, W2, a2u, flags);
    k_gather2<<<4096, 256, 0, stream>>>(rowptr, srcidx, a2u, dinv, b2, d_out, flags);
    k_pool<<<512, 256, 0, stream>>>(d_out, bat, gsum, flags);
    k_gout<<<(N_GRAPHS * 64 + 255) / 256, 256, 0, stream>>>(gsum, bat, d_out, flags);
}